// Round 1
// baseline (90.633 us; speedup 1.0000x reference)
//
#include <hip/hip_runtime.h>

// Problem constants (from reference setup_inputs)
#define NN 8
#define CC 4
#define HH 64
#define WW 64
#define KK 5
#define FF 16
#define HO 60
#define WO 60
#define PP (KK * KK * CC) /* 100 */

// ws layout: [0, 25600): weight quads (A1,B1,A2,B2) per (p,f), 1600 float4
//            [25600, 25600+2MiB): pixel quads (E1,XE1,E2,XE2) per (n,c,h,w)
#define WQ_BYTES (PP * FF * 16)

__global__ void smorph_weights(const float* __restrict__ k1,
                               const float* __restrict__ k2,
                               float4* __restrict__ wq) {
    int i = blockIdx.x * blockDim.x + threadIdx.x;
    if (i < PP * FF) {
        float a = k1[i], b = k2[i];
        float ea = __expf(a), eb = __expf(b);
        wq[i] = make_float4(ea, a * ea, eb, b * eb);
    }
}

__global__ void smorph_pixels(const float* __restrict__ x,
                              float4* __restrict__ pq) {
    int i = blockIdx.x * blockDim.x + threadIdx.x; // 131072 total, exact
    float v = x[i];
    float e1 = __expf(v);
    float e2 = __expf(-v);
    pq[i] = make_float4(e1, v * e1, e2, -v * e2);
}

// block = 256: threads [0,128) do f 0..7, [128,256) do f 8..15 -> each wave
// is f-uniform so the LDS weight reads are wave-uniform broadcasts.
__global__ __launch_bounds__(256) void smorph_conv(
        const float4* __restrict__ pq, const float4* __restrict__ wq,
        const float* __restrict__ bias, float* __restrict__ out) {
    __shared__ float4 w[PP * FF]; // 25.6 KB
    for (int i = threadIdx.x; i < PP * FF; i += 256) w[i] = wq[i];
    __syncthreads();

    int t = threadIdx.x;
    int fg = t >> 7;                       // feature group 0/1
    int idx = blockIdx.x * 128 + (t & 127); // output pixel id, < 28800 exact
    int n = idx / (HO * WO);
    int r = idx % (HO * WO);
    int ho = r / WO;
    int wo = r % WO;

    float d1[8], n1[8], d2[8], n2[8];
#pragma unroll
    for (int j = 0; j < 8; ++j) { d1[j] = 0.f; n1[j] = 0.f; d2[j] = 0.f; n2[j] = 0.f; }

#pragma unroll 1
    for (int c = 0; c < CC; ++c) {
#pragma unroll 1
        for (int kh = 0; kh < KK; ++kh) {
            const float4* row = pq + ((size_t)(n * CC + c) * HH + (ho + kh)) * WW + wo;
            const float4* wbase = &w[((kh * KK) * CC + c) * FF + fg * 8];
#pragma unroll
            for (int kw = 0; kw < KK; ++kw) {
                float4 q = row[kw];
                const float4* wp = wbase + kw * (CC * FF);
#pragma unroll
                for (int j = 0; j < 8; ++j) {
                    float4 ww = wp[j];
                    d1[j] = fmaf(q.x, ww.x, d1[j]);
                    n1[j] = fmaf(q.y, ww.x, n1[j]);
                    n1[j] = fmaf(q.x, ww.y, n1[j]);
                    d2[j] = fmaf(q.z, ww.z, d2[j]);
                    n2[j] = fmaf(q.w, ww.z, n2[j]);
                    n2[j] = fmaf(q.z, ww.w, n2[j]);
                }
            }
        }
    }

#pragma unroll
    for (int j = 0; j < 8; ++j) {
        int f = fg * 8 + j;
        float y = n1[j] / d1[j] + n2[j] / d2[j] + bias[f];
        out[((size_t)(n * FF + f) * HO + ho) * WO + wo] = y;
    }
}

extern "C" void kernel_launch(void* const* d_in, const int* in_sizes, int n_in,
                              void* d_out, int out_size, void* d_ws, size_t ws_size,
                              hipStream_t stream) {
    const float* x    = (const float*)d_in[0];
    const float* k1   = (const float*)d_in[1];
    const float* k2   = (const float*)d_in[2];
    const float* bias = (const float*)d_in[3];
    float* out = (float*)d_out;

    float4* wq = (float4*)d_ws;
    float4* pq = (float4*)((char*)d_ws + WQ_BYTES);

    smorph_weights<<<(PP * FF + 255) / 256, 256, 0, stream>>>(k1, k2, wq);
    smorph_pixels<<<(NN * CC * HH * WW) / 256, 256, 0, stream>>>(x, pq);
    // 28800 output pixels * 2 feature-groups = 57600 threads = 225 blocks
    smorph_conv<<<225, 256, 0, stream>>>(pq, wq, bias, out);
}

// Round 2
// 83.149 us; speedup vs baseline: 1.0900x; 1.0900x over previous
//
#include <hip/hip_runtime.h>

// Problem constants (from reference setup_inputs)
#define NN 8
#define CC 4
#define HH 64
#define WW 64
#define KK 5
#define FF 16
#define HO 60
#define WO 60
#define PP (KK * KK * CC) /* 100 */

// ws layout: [0, 25600): weight quads (A1,B1,A2,B2) per (p,f), 1600 float4
// A1=e^k1, B1=k1*e^k1, A2=e^k2, B2=k2*e^k2

__global__ void smorph_weights(const float* __restrict__ k1,
                               const float* __restrict__ k2,
                               float4* __restrict__ wq) {
    int i = blockIdx.x * blockDim.x + threadIdx.x;
    if (i < PP * FF) {
        float a = k1[i], b = k2[i];
        float ea = __expf(a), eb = __expf(b);
        wq[i] = make_float4(ea, a * ea, eb, b * eb);
    }
}

// Block = one (n, ho) output row strip: 64 lanes <-> w positions (60 used),
// 4 waves <-> 4 features each (wave v covers f = 4v..4v+3).
// Pixel exp-quads (E1, x*E1, E2, -x*E2) staged in LDS (5 rows x 4c x 64w).
// Weight quads are wave-uniform -> scalar loads (constant cache, free pipe).
__global__ __launch_bounds__(256) void smorph_conv(
        const float* __restrict__ x, const float4* __restrict__ wq,
        const float* __restrict__ bias, float* __restrict__ out) {
    __shared__ float4 pq[CC * KK * 64 + 4]; // +4 pad: lanes 60-63 read wo+kw<=67

    int b = blockIdx.x; // 0..479 = (n, ho)
    int n = b / HO;
    int ho = b % HO;
    int t = threadIdx.x;

    // Stage: rows ho..ho+4 (always in-bounds: ho+4 <= 63), all c, w 0..63.
    // 1280 pixels / 256 threads = 5 iterations, coalesced in w.
    for (int i = t; i < CC * KK * 64; i += 256) {
        int w = i & 63;
        int cr = i >> 6; // c*KK + r
        int c = cr / KK, r = cr - c * KK;
        float v = x[((n * CC + c) * HH + (ho + r)) * WW + w];
        float e1 = __expf(v), e2 = __expf(-v);
        pq[i] = make_float4(e1, v * e1, e2, -v * e2);
    }
    __syncthreads();

    int lane = t & 63; // w position
    int fbase = __builtin_amdgcn_readfirstlane(t >> 6) * 4; // wave-uniform

    float d1[4] = {0.f, 0.f, 0.f, 0.f}, n1[4] = {0.f, 0.f, 0.f, 0.f};
    float d2[4] = {0.f, 0.f, 0.f, 0.f}, n2[4] = {0.f, 0.f, 0.f, 0.f};

#pragma unroll 1
    for (int c = 0; c < CC; ++c) {
#pragma unroll
        for (int kh = 0; kh < KK; ++kh) {
            const float4* prow = &pq[(c * KK + kh) * 64 + lane];
#pragma unroll
            for (int kw = 0; kw < KK; ++kw) {
                float4 q = prow[kw]; // ds_read_b128, consecutive lanes
                // p = (kh*KK + kw)*CC + c  (reference patch order: kh,kw,c)
                const float4* wp = wq + ((kh * KK + kw) * CC + c) * FF + fbase;
#pragma unroll
                for (int j = 0; j < 4; ++j) {
                    float4 ww = wp[j]; // uniform addr -> s_load_dwordx4
                    d1[j] = fmaf(q.x, ww.x, d1[j]);
                    n1[j] = fmaf(q.y, ww.x, n1[j]);
                    n1[j] = fmaf(q.x, ww.y, n1[j]);
                    d2[j] = fmaf(q.z, ww.z, d2[j]);
                    n2[j] = fmaf(q.w, ww.z, n2[j]);
                    n2[j] = fmaf(q.z, ww.w, n2[j]);
                }
            }
        }
    }

    if (lane < WO) {
#pragma unroll
        for (int j = 0; j < 4; ++j) {
            int f = fbase + j;
            out[((size_t)(n * FF + f) * HO + ho) * WO + lane] =
                n1[j] / d1[j] + n2[j] / d2[j] + bias[f];
        }
    }
}

extern "C" void kernel_launch(void* const* d_in, const int* in_sizes, int n_in,
                              void* d_out, int out_size, void* d_ws, size_t ws_size,
                              hipStream_t stream) {
    const float* x    = (const float*)d_in[0];
    const float* k1   = (const float*)d_in[1];
    const float* k2   = (const float*)d_in[2];
    const float* bias = (const float*)d_in[3];
    float* out = (float*)d_out;

    float4* wq = (float4*)d_ws;

    smorph_weights<<<(PP * FF + 255) / 256, 256, 0, stream>>>(k1, k2, wq);
    // 8 n * 60 ho = 480 blocks, 256 threads (4 waves: one per 4-feature group)
    smorph_conv<<<480, 256, 0, stream>>>(x, wq, bias, out);
}